// Round 1
// baseline (332.711 us; speedup 1.0000x reference)
//
#include <hip/hip_runtime.h>
#include <hip/hip_bf16.h>
#include <math.h>

typedef __hip_bfloat16 bf16;
typedef __attribute__((ext_vector_type(4))) float f32x4;
typedef __attribute__((ext_vector_type(8))) short s16x8;

typedef const __attribute__((address_space(1))) void gvoid_t;
typedef __attribute__((address_space(3))) void lvoid_t;

__device__ __forceinline__ void gload16(const void* g, void* l) {
  // async global->LDS, 16B per lane; LDS dest is wave-uniform base + lane*16
  __builtin_amdgcn_global_load_lds((gvoid_t*)g, (lvoid_t*)l, 16, 0, 0);
}

// ---------------- prep: build x = concat(patches, positions) as bf16 [16384][832]
__global__ __launch_bounds__(256) void prep_x(const float* __restrict__ patches,
                                              const float* __restrict__ positions,
                                              bf16* __restrict__ xb) {
  const long long row = blockIdx.x;  // 16384 rows
  const float* pr = patches + row * 768;
  const float* ps = positions + row * 64;
  bf16* xr = xb + row * 832;
  for (int c = threadIdx.x; c < 832; c += 256) {
    float v = (c < 768) ? pr[c] : ps[c - 768];
    xr[c] = __float2bfloat16(v);
  }
}

// ---------------- prep: Wt[z][n][k] = W_z[k][n] cast to bf16 (832x512 -> 512x832)
__global__ __launch_bounds__(256) void prep_w(const float* __restrict__ Wq,
                                              const float* __restrict__ Wk,
                                              const float* __restrict__ Wv,
                                              bf16* __restrict__ Wt) {
  __shared__ float tile[32][33];
  const int z = blockIdx.z;
  const float* W = (z == 0) ? Wq : (z == 1) ? Wk : Wv;
  bf16* T = Wt + (long long)z * 512 * 832;
  const int n0 = blockIdx.x * 32;  // 512/32 = 16
  const int k0 = blockIdx.y * 32;  // 832/32 = 26
  const int tx = threadIdx.x, ty = threadIdx.y;  // (32,8)
  #pragma unroll
  for (int i = 0; i < 32; i += 8)
    tile[ty + i][tx] = W[(long long)(k0 + ty + i) * 512 + n0 + tx];
  __syncthreads();
  #pragma unroll
  for (int i = 0; i < 32; i += 8)
    T[(long long)(n0 + ty + i) * 832 + k0 + tx] = __float2bfloat16(tile[tx][ty + i]);
}

// ---------------- prep: VT[b][d][j] = V[b][j][d]  (bf16 2048x512 -> 512x2048 per batch)
__global__ __launch_bounds__(256) void prep_vt(const bf16* __restrict__ V,
                                               bf16* __restrict__ VT) {
  __shared__ bf16 tile[32][33];
  const int b = blockIdx.z;
  const bf16* Vb = V + (long long)b * 2048 * 512;
  bf16* Tb = VT + (long long)b * 512 * 2048;
  const int d0 = blockIdx.x * 32;  // 512/32 = 16
  const int j0 = blockIdx.y * 32;  // 2048/32 = 64
  const int tx = threadIdx.x, ty = threadIdx.y;  // (32,8)
  #pragma unroll
  for (int i = 0; i < 32; i += 8)
    tile[ty + i][tx] = Vb[(long long)(j0 + ty + i) * 512 + d0 + tx];
  __syncthreads();
  #pragma unroll
  for (int i = 0; i < 32; i += 8)
    Tb[(long long)(d0 + ty + i) * 2048 + j0 + tx] = tile[tx][ty + i];
}

// ---------------- batched NT GEMM, m97 structure: C = A(MxK) * BT(NxK)^T
// MODE 0: bf16 out = acc + bias[n]   (QKV projection, z selects bias)
// MODE 1: bf16 out = acc * alpha     (scores)
// MODE 2: f32  out = acc             (PV)
template <int MODE>
__global__ __launch_bounds__(256) void gemm_nt(
    const bf16* __restrict__ A, const bf16* __restrict__ Bt, void* __restrict__ Cp,
    const float* __restrict__ bias0, const float* __restrict__ bias1,
    const float* __restrict__ bias2,
    int M, int N, int K, int lda, int ldb, int ldc,
    long long sA, long long sB, long long sC, float alpha) {
  __shared__ bf16 As[128 * 64];
  __shared__ bf16 Bs[128 * 64];

  const int z = blockIdx.z;
  const bf16* Ab = A + (long long)z * sA;
  const bf16* Bb = Bt + (long long)z * sB;

  const int tid = threadIdx.x;
  const int wave = tid >> 6;
  const int lane = tid & 63;
  const int llo = lane & 15;
  const int lhi = lane >> 4;
  const int wm = wave >> 1;  // 2x2 wave grid, each wave does 64x64
  const int wn = wave & 1;

  const int bm = blockIdx.y * 128;
  const int bn = blockIdx.x * 128;

  f32x4 acc[4][4] = {};

  for (int kt = 0; kt < K; kt += 64) {
    // stage 128x64 bf16 tiles of A and BT: 1024 chunks of 16B each, 4 per thread
    #pragma unroll
    for (int i = 0; i < 4; i++) {
      const int c = i * 256 + tid;
      const int r = c >> 3;             // tile row
      const int k8 = (c & 7) << 3;      // elem offset in row
      const void* ga = Ab + ((long long)(bm + r) * lda + kt + k8);
      const void* gb = Bb + ((long long)(bn + r) * ldb + kt + k8);
      void* la = (char*)As + (long long)(i * 256 + wave * 64) * 16;  // wave-uniform
      void* lb = (char*)Bs + (long long)(i * 256 + wave * 64) * 16;
      gload16(ga, la);
      gload16(gb, lb);
    }
    __syncthreads();  // compiler emits vmcnt(0) drain before barrier
    #pragma unroll
    for (int k0 = 0; k0 < 64; k0 += 32) {
      s16x8 af[4], bfr[4];
      #pragma unroll
      for (int mf = 0; mf < 4; mf++)
        af[mf] = *(const s16x8*)&As[(wm * 64 + mf * 16 + llo) * 64 + k0 + lhi * 8];
      #pragma unroll
      for (int nf = 0; nf < 4; nf++)
        bfr[nf] = *(const s16x8*)&Bs[(wn * 64 + nf * 16 + llo) * 64 + k0 + lhi * 8];
      #pragma unroll
      for (int mf = 0; mf < 4; mf++) {
        #pragma unroll
        for (int nf = 0; nf < 4; nf++)
          acc[mf][nf] = __builtin_amdgcn_mfma_f32_16x16x32_bf16(
              af[mf], bfr[nf], acc[mf][nf], 0, 0, 0);
      }
    }
    __syncthreads();
  }

  // epilogue: C/D layout col=lane&15, row=(lane>>4)*4+reg
  const float* bias = (z == 0) ? bias0 : (z == 1) ? bias1 : bias2;
  const long long cbase = (long long)z * sC;
  #pragma unroll
  for (int mf = 0; mf < 4; mf++) {
    #pragma unroll
    for (int nf = 0; nf < 4; nf++) {
      const int gcol = bn + wn * 64 + nf * 16 + llo;
      const int grow0 = bm + wm * 64 + mf * 16 + lhi * 4;
      float bv_ = (MODE == 0) ? bias[gcol] : 0.0f;
      #pragma unroll
      for (int r = 0; r < 4; r++) {
        const long long idx = cbase + (long long)(grow0 + r) * ldc + gcol;
        const float v = acc[mf][nf][r];
        if (MODE == 0) {
          ((bf16*)Cp)[idx] = __float2bfloat16(v + bv_);
        } else if (MODE == 1) {
          ((bf16*)Cp)[idx] = __float2bfloat16(v * alpha);
        } else {
          ((float*)Cp)[idx] = v;
        }
      }
    }
  }
}

// ---------------- row softmax, in place on bf16 [16384][2048]
__global__ __launch_bounds__(256) void softmax_rows(bf16* __restrict__ S) {
  const long long row = blockIdx.x;
  bf16* p = S + row * 2048;
  const int tid = threadIdx.x;
  const int lane = tid & 63;
  const int wave = tid >> 6;
  __shared__ float redm[4], reds[4];
  float v[8];
  float mx = -3.0e38f;
  #pragma unroll
  for (int i = 0; i < 8; i++) {
    v[i] = __bfloat162float(p[tid + i * 256]);
    mx = fmaxf(mx, v[i]);
  }
  #pragma unroll
  for (int off = 32; off > 0; off >>= 1) mx = fmaxf(mx, __shfl_xor(mx, off, 64));
  if (lane == 0) redm[wave] = mx;
  __syncthreads();
  mx = fmaxf(fmaxf(redm[0], redm[1]), fmaxf(redm[2], redm[3]));
  float s = 0.f;
  #pragma unroll
  for (int i = 0; i < 8; i++) {
    v[i] = __expf(v[i] - mx);
    s += v[i];
  }
  #pragma unroll
  for (int off = 32; off > 0; off >>= 1) s += __shfl_xor(s, off, 64);
  if (lane == 0) reds[wave] = s;
  __syncthreads();
  s = reds[0] + reds[1] + reds[2] + reds[3];
  const float inv = 1.0f / s;
  #pragma unroll
  for (int i = 0; i < 8; i++)
    p[tid + i * 256] = __float2bfloat16(v[i] * inv);
}

extern "C" void kernel_launch(void* const* d_in, const int* in_sizes, int n_in,
                              void* d_out, int out_size, void* d_ws, size_t ws_size,
                              hipStream_t stream) {
  const float* patches = (const float*)d_in[0];
  const float* positions = (const float*)d_in[1];
  const float* Wq = (const float*)d_in[2];
  const float* bq = (const float*)d_in[3];
  const float* Wk = (const float*)d_in[4];
  const float* bk = (const float*)d_in[5];
  const float* Wv = (const float*)d_in[6];
  const float* bv = (const float*)d_in[7];
  float* out = (float*)d_out;

  char* ws = (char*)d_ws;
  // workspace layout (all 16B-aligned):
  bf16* Wt  = (bf16*)(ws);              // 3*512*832*2   = 2,555,904
  bf16* xb  = (bf16*)(ws + 2555904);    // 16384*832*2   = 27,262,976
  bf16* qkv = (bf16*)(ws + 29818880);   // 3*16384*512*2 = 50,331,648
  bf16* vt  = (bf16*)(ws + 80150528);   // 8*512*2048*2  = 16,777,216
  bf16* S   = (bf16*)(ws + 96927744);   // 8*2048*2048*2 = 67,108,864
  // total: 164,036,608 bytes

  bf16* Q  = qkv;
  bf16* Km = qkv + (long long)16384 * 512;
  bf16* V  = qkv + (long long)2 * 16384 * 512;

  prep_x<<<16384, 256, 0, stream>>>(patches, positions, xb);
  prep_w<<<dim3(16, 26, 3), dim3(32, 8), 0, stream>>>(Wq, Wk, Wv, Wt);

  // QKV: [16384,832] x [832,512] -> bf16 [3][16384][512], + bias
  gemm_nt<0><<<dim3(4, 128, 3), 256, 0, stream>>>(
      xb, Wt, qkv, bq, bk, bv,
      16384, 512, 832, 832, 832, 512,
      0LL, (long long)512 * 832, (long long)16384 * 512, 1.0f);

  prep_vt<<<dim3(16, 64, 8), dim3(32, 8), 0, stream>>>(V, vt);

  // S[b] = Q[b] * K[b]^T / sqrt(512) -> bf16 [8][2048][2048]
  gemm_nt<1><<<dim3(16, 16, 8), 256, 0, stream>>>(
      Q, Km, S, nullptr, nullptr, nullptr,
      2048, 2048, 512, 512, 512, 2048,
      (long long)2048 * 512, (long long)2048 * 512, (long long)2048 * 2048,
      0.044194173824159216f);

  softmax_rows<<<16384, 256, 0, stream>>>(S);

  // O[b] = P[b] * V[b] -> f32 [8][2048][512] into d_out
  gemm_nt<2><<<dim3(4, 16, 8), 256, 0, stream>>>(
      S, vt, out, nullptr, nullptr, nullptr,
      2048, 512, 2048, 2048, 2048, 512,
      (long long)2048 * 2048, (long long)512 * 2048, (long long)2048 * 512, 1.0f);
}

// Round 4
// 281.448 us; speedup vs baseline: 1.1821x; 1.1821x over previous
//
#include <hip/hip_runtime.h>
#include <hip/hip_bf16.h>
#include <math.h>

typedef __hip_bfloat16 bf16;
typedef __attribute__((ext_vector_type(4))) float f32x4;
typedef __attribute__((ext_vector_type(8))) short s16x8;

typedef const __attribute__((address_space(1))) void gvoid_t;
typedef __attribute__((address_space(3))) void lvoid_t;

__device__ __forceinline__ void gload16(const void* g, void* l) {
  // async global->LDS, 16B/lane; LDS dest is wave-uniform base + lane*16
  __builtin_amdgcn_global_load_lds((gvoid_t*)g, (lvoid_t*)l, 16, 0, 0);
}
__device__ __forceinline__ float b2f(unsigned short u) {
  return __uint_as_float(((unsigned int)u) << 16);
}
__device__ __forceinline__ unsigned short f2b(float f) {
  bf16 h = __float2bfloat16(f);
  return *(unsigned short*)&h;
}

// ---------------- prep: x = concat(patches, positions) -> bf16 [16384][832]
// fully predicated (no early return); 208 active lanes of 256
__global__ __launch_bounds__(256) void prep_x(const float* __restrict__ patches,
                                              const float* __restrict__ positions,
                                              bf16* __restrict__ xb) {
  const long long row = blockIdx.x;
  const int c = threadIdx.x;
  const bool lo = (c < 192);
  const bool hi = (c >= 192) && (c < 208);
  const float* src = lo ? (patches + row * 768 + c * 4)
                        : (positions + row * 64 + (c - 192) * 4);
  if (lo || hi) {
    float4 v = *(const float4*)src;
    const int dst = lo ? (c * 4) : (768 + (c - 192) * 4);
    uint2 w;
    w.x = (unsigned int)f2b(v.x) | ((unsigned int)f2b(v.y) << 16);
    w.y = (unsigned int)f2b(v.z) | ((unsigned int)f2b(v.w) << 16);
    *(uint2*)(xb + row * 832 + dst) = w;
  }
}

// ---------------- prep: Wt[z*512+n][k] = W_z[k][n] bf16 (832x512 -> 512x832)
__global__ __launch_bounds__(256) void prep_w(const float* __restrict__ Wq,
                                              const float* __restrict__ Wk,
                                              const float* __restrict__ Wv,
                                              bf16* __restrict__ Wt) {
  __shared__ float tile[32][33];
  const int z = blockIdx.z;
  const float* W = (z == 0) ? Wq : (z == 1) ? Wk : Wv;
  bf16* T = Wt + (long long)z * 512 * 832;
  const int n0 = blockIdx.x * 32;
  const int k0 = blockIdx.y * 32;
  const int tx = threadIdx.x, ty = threadIdx.y;  // (32,8)
  #pragma unroll
  for (int i = 0; i < 32; i += 8)
    tile[ty + i][tx] = W[(long long)(k0 + ty + i) * 512 + n0 + tx];
  __syncthreads();
  #pragma unroll
  for (int i = 0; i < 32; i += 8)
    T[(long long)(n0 + ty + i) * 832 + k0 + tx] = __float2bfloat16(tile[tx][ty + i]);
}

// ---------------- fused QKV projection: [16384,832] x [1536,832]^T
// z<2 -> qk[z][row][c] = acc + bias (bf16); z==2 -> vt[b][c][j] = acc + bv[c]
// (V transposed, 8B packed stores). XCD-chunked tiles; XOR k-chunk swizzle
// (slot = cc ^ (r&7), realized via the global address since global_load_lds
// pins the LDS layout) breaks the 16-way ds_read_b128 bank conflict.
__global__ __launch_bounds__(256) void gemm_qkv(
    const bf16* __restrict__ xb, const bf16* __restrict__ Wt,
    const float* __restrict__ bq, const float* __restrict__ bk,
    const float* __restrict__ bv,
    bf16* __restrict__ qk, bf16* __restrict__ vt) {
  __shared__ bf16 As[128 * 64];
  __shared__ bf16 Bs[128 * 64];
  const int tid = threadIdx.x;
  const int wave = tid >> 6, lane = tid & 63;
  const int llo = lane & 15, lhi = lane >> 4;
  const int wm = wave >> 1, wn = wave & 1;

  const unsigned int lin = blockIdx.x;        // 1536 blocks
  const unsigned int xcd = lin & 7u, idx = lin >> 3;
  const unsigned int g = xcd * 192u + idx;    // per-XCD contiguous chunk
  const unsigned int bm_t = g / 12u;          // 0..127
  const unsigned int bn_t = g - bm_t * 12u;   // 0..11, fastest
  const int row0 = (int)bm_t * 128;
  const int col0 = (int)bn_t * 128;
  const int z = col0 >> 9;

  f32x4 acc[4][4] = {};

  for (int kt = 0; kt < 832; kt += 64) {
    #pragma unroll
    for (int i = 0; i < 4; i++) {
      const int c = i * 256 + tid;
      const int r = c >> 3, cc = c & 7;
      const int kk = (cc ^ (r & 7)) << 3;
      gload16(xb + ((long long)(row0 + r) * 832 + kt + kk),
              (char*)As + (long long)(i * 256 + wave * 64) * 16);
      gload16(Wt + ((long long)(col0 + r) * 832 + kt + kk),
              (char*)Bs + (long long)(i * 256 + wave * 64) * 16);
    }
    __syncthreads();
    #pragma unroll
    for (int k0 = 0; k0 < 64; k0 += 32) {
      const int xk = ((((k0 >> 3) + lhi) ^ (llo & 7)) << 3);
      s16x8 af[4], bfr[4];
      #pragma unroll
      for (int mf = 0; mf < 4; mf++)
        af[mf] = *(const s16x8*)&As[(wm * 64 + mf * 16 + llo) * 64 + xk];
      #pragma unroll
      for (int nf = 0; nf < 4; nf++)
        bfr[nf] = *(const s16x8*)&Bs[(wn * 64 + nf * 16 + llo) * 64 + xk];
      #pragma unroll
      for (int mf = 0; mf < 4; mf++)
        #pragma unroll
        for (int nf = 0; nf < 4; nf++)
          acc[mf][nf] = __builtin_amdgcn_mfma_f32_16x16x32_bf16(
              af[mf], bfr[nf], acc[mf][nf], 0, 0, 0);
    }
    __syncthreads();
  }

  // epilogue: C/D layout col=lane&15, row=(lane>>4)*4+reg
  if (z < 2) {
    const float* bias = z ? bk : bq;
    bf16* outp = qk + (long long)z * 16384 * 512;
    #pragma unroll
    for (int mf = 0; mf < 4; mf++)
      #pragma unroll
      for (int nf = 0; nf < 4; nf++) {
        const int c = (col0 & 511) + wn * 64 + nf * 16 + llo;
        const int grow0 = row0 + wm * 64 + mf * 16 + lhi * 4;
        const float bb = bias[c];
        #pragma unroll
        for (int r = 0; r < 4; r++)
          outp[(long long)(grow0 + r) * 512 + c] =
              __float2bfloat16(acc[mf][nf][r] + bb);
      }
  } else {
    #pragma unroll
    for (int mf = 0; mf < 4; mf++)
      #pragma unroll
      for (int nf = 0; nf < 4; nf++) {
        const int c = (col0 & 511) + wn * 64 + nf * 16 + llo;
        const int grow0 = row0 + wm * 64 + mf * 16 + lhi * 4;
        const int b = grow0 >> 11, j = grow0 & 2047;  // 4 rows stay in-batch
        const float bb = bv[c];
        uint2 w;
        w.x = (unsigned int)f2b(acc[mf][nf][0] + bb) |
              ((unsigned int)f2b(acc[mf][nf][1] + bb) << 16);
        w.y = (unsigned int)f2b(acc[mf][nf][2] + bb) |
              ((unsigned int)f2b(acc[mf][nf][3] + bb) << 16);
        *(uint2*)(vt + (long long)b * 512 * 2048 + (long long)c * 2048 + j) = w;
      }
  }
}

// ---------------- scores: S[b] = Q[b] K[b]^T * alpha, bf16 out; 1 batch/XCD
__global__ __launch_bounds__(256) void gemm_scores(const bf16* __restrict__ qk,
                                                   bf16* __restrict__ S) {
  __shared__ bf16 As[128 * 64];
  __shared__ bf16 Bs[128 * 64];
  const int tid = threadIdx.x;
  const int wave = tid >> 6, lane = tid & 63;
  const int llo = lane & 15, lhi = lane >> 4;
  const int wm = wave >> 1, wn = wave & 1;

  const unsigned int lin = blockIdx.x;  // 2048
  const unsigned int xcd = lin & 7u, idx = lin >> 3;
  const unsigned int g = xcd * 256u + idx;
  const int b = (int)(g >> 8);
  const unsigned int rem = g & 255u;
  const int row0 = (int)(rem >> 4) * 128;
  const int col0 = (int)(rem & 15u) * 128;

  const bf16* Ab = qk + (long long)b * 2048 * 512;                           // Q
  const bf16* Bb = qk + (long long)16384 * 512 + (long long)b * 2048 * 512;  // K

  f32x4 acc[4][4] = {};
  for (int kt = 0; kt < 512; kt += 64) {
    #pragma unroll
    for (int i = 0; i < 4; i++) {
      const int c = i * 256 + tid;
      const int r = c >> 3, cc = c & 7;
      const int kk = (cc ^ (r & 7)) << 3;
      gload16(Ab + ((long long)(row0 + r) * 512 + kt + kk),
              (char*)As + (long long)(i * 256 + wave * 64) * 16);
      gload16(Bb + ((long long)(col0 + r) * 512 + kt + kk),
              (char*)Bs + (long long)(i * 256 + wave * 64) * 16);
    }
    __syncthreads();
    #pragma unroll
    for (int k0 = 0; k0 < 64; k0 += 32) {
      const int xk = ((((k0 >> 3) + lhi) ^ (llo & 7)) << 3);
      s16x8 af[4], bfr[4];
      #pragma unroll
      for (int mf = 0; mf < 4; mf++)
        af[mf] = *(const s16x8*)&As[(wm * 64 + mf * 16 + llo) * 64 + xk];
      #pragma unroll
      for (int nf = 0; nf < 4; nf++)
        bfr[nf] = *(const s16x8*)&Bs[(wn * 64 + nf * 16 + llo) * 64 + xk];
      #pragma unroll
      for (int mf = 0; mf < 4; mf++)
        #pragma unroll
        for (int nf = 0; nf < 4; nf++)
          acc[mf][nf] = __builtin_amdgcn_mfma_f32_16x16x32_bf16(
              af[mf], bfr[nf], acc[mf][nf], 0, 0, 0);
    }
    __syncthreads();
  }

  bf16* Sb = S + (long long)b * 2048 * 2048;
  const float alpha = 0.044194173824159216f;  // 1/sqrt(512)
  #pragma unroll
  for (int mf = 0; mf < 4; mf++)
    #pragma unroll
    for (int nf = 0; nf < 4; nf++) {
      const int gcol = col0 + wn * 64 + nf * 16 + llo;
      const int grow0 = row0 + wm * 64 + mf * 16 + lhi * 4;
      #pragma unroll
      for (int r = 0; r < 4; r++)
        Sb[(long long)(grow0 + r) * 2048 + gcol] =
            __float2bfloat16(acc[mf][nf][r] * alpha);
    }
}

// ---------------- row softmax in place, bf16 [16384][2048], 16B vector IO
__global__ __launch_bounds__(256) void softmax_rows(bf16* __restrict__ S) {
  const long long row = blockIdx.x;
  bf16* p = S + row * 2048;
  const int tid = threadIdx.x;
  const int lane = tid & 63, wave = tid >> 6;
  __shared__ float redm[4], reds[4];
  uint4 raw = *(const uint4*)(p + tid * 8);
  const unsigned short* us = (const unsigned short*)&raw;
  float v[8];
  float mx = -3.0e38f;
  #pragma unroll
  for (int i = 0; i < 8; i++) {
    v[i] = b2f(us[i]);
    mx = fmaxf(mx, v[i]);
  }
  #pragma unroll
  for (int off = 32; off > 0; off >>= 1) mx = fmaxf(mx, __shfl_xor(mx, off, 64));
  if (lane == 0) redm[wave] = mx;
  __syncthreads();
  mx = fmaxf(fmaxf(redm[0], redm[1]), fmaxf(redm[2], redm[3]));
  float s = 0.f;
  #pragma unroll
  for (int i = 0; i < 8; i++) {
    v[i] = __expf(v[i] - mx);
    s += v[i];
  }
  #pragma unroll
  for (int off = 32; off > 0; off >>= 1) s += __shfl_xor(s, off, 64);
  if (lane == 0) reds[wave] = s;
  __syncthreads();
  const float inv = 1.0f / (reds[0] + reds[1] + reds[2] + reds[3]);
  uint4 o;
  o.x = (unsigned int)f2b(v[0] * inv) | ((unsigned int)f2b(v[1] * inv) << 16);
  o.y = (unsigned int)f2b(v[2] * inv) | ((unsigned int)f2b(v[3] * inv) << 16);
  o.z = (unsigned int)f2b(v[4] * inv) | ((unsigned int)f2b(v[5] * inv) << 16);
  o.w = (unsigned int)f2b(v[6] * inv) | ((unsigned int)f2b(v[7] * inv) << 16);
  *(uint4*)(p + tid * 8) = o;
}

// ---------------- PV: out[b] = P[b] (2048x2048) x V[b] (2048x512), fp32 out
// BM=64 BN=128 -> 1024 blocks, 24KB LDS -> 6 blocks/CU; one batch per XCD.
__global__ __launch_bounds__(256) void gemm_pv(const bf16* __restrict__ S,
                                               const bf16* __restrict__ vt,
                                               float* __restrict__ out) {
  __shared__ bf16 As[64 * 64];    // 8 KB
  __shared__ bf16 Bs[128 * 64];   // 16 KB
  const int tid = threadIdx.x;
  const int wave = tid >> 6, lane = tid & 63;
  const int llo = lane & 15, lhi = lane >> 4;
  const int wm = wave >> 1, wn = wave & 1;  // wave = 32x64 of the 64x128 tile

  const unsigned int lin = blockIdx.x;  // 1024
  const unsigned int xcd = lin & 7u, idx = lin >> 3;
  const unsigned int g = xcd * 128u + idx;
  const int b = (int)(g >> 7);
  const unsigned int rem = g & 127u;
  const int row0 = (int)(rem >> 2) * 64;
  const int col0 = (int)(rem & 3u) * 128;

  const bf16* Ab = S + (long long)b * 2048 * 2048;
  const bf16* Bb = vt + (long long)b * 512 * 2048;

  f32x4 acc[2][4] = {};
  for (int kt = 0; kt < 2048; kt += 64) {
    #pragma unroll
    for (int i = 0; i < 2; i++) {
      const int c = i * 256 + tid;
      const int r = c >> 3, cc = c & 7;
      const int kk = (cc ^ (r & 7)) << 3;
      gload16(Ab + ((long long)(row0 + r) * 2048 + kt + kk),
              (char*)As + (long long)(i * 256 + wave * 64) * 16);
    }
    #pragma unroll
    for (int i = 0; i < 4; i++) {
      const int c = i * 256 + tid;
      const int r = c >> 3, cc = c & 7;
      const int kk = (cc ^ (r & 7)) << 3;
      gload16(Bb + ((long long)(col0 + r) * 2048 + kt + kk),
              (char*)Bs + (long long)(i * 256 + wave * 64) * 16);
    }
    __syncthreads();
    #pragma unroll
    for (int k0 = 0; k0 < 64; k0 += 32) {
      const int xk = ((((k0 >> 3) + lhi) ^ (llo & 7)) << 3);
      s16x8 af[2], bfr[4];
      #pragma unroll
      for (int mf = 0; mf < 2; mf++)
        af[mf] = *(const s16x8*)&As[(wm * 32 + mf * 16 + llo) * 64 + xk];
      #pragma unroll
      for (int nf = 0; nf < 4; nf++)
        bfr[nf] = *(const s16x8*)&Bs[(wn * 64 + nf * 16 + llo) * 64 + xk];
      #pragma unroll
      for (int mf = 0; mf < 2; mf++)
        #pragma unroll
        for (int nf = 0; nf < 4; nf++)
          acc[mf][nf] = __builtin_amdgcn_mfma_f32_16x16x32_bf16(
              af[mf], bfr[nf], acc[mf][nf], 0, 0, 0);
    }
    __syncthreads();
  }

  float* Ob = out + (long long)b * 2048 * 512;
  #pragma unroll
  for (int mf = 0; mf < 2; mf++)
    #pragma unroll
    for (int nf = 0; nf < 4; nf++) {
      const int gcol = col0 + wn * 64 + nf * 16 + llo;
      const int grow0 = row0 + wm * 32 + mf * 16 + lhi * 4;
      #pragma unroll
      for (int r = 0; r < 4; r++)
        Ob[(long long)(grow0 + r) * 512 + gcol] = acc[mf][nf][r];
    }
}

extern "C" void kernel_launch(void* const* d_in, const int* in_sizes, int n_in,
                              void* d_out, int out_size, void* d_ws, size_t ws_size,
                              hipStream_t stream) {
  const float* patches = (const float*)d_in[0];
  const float* positions = (const float*)d_in[1];
  const float* Wq = (const float*)d_in[2];
  const float* bq = (const float*)d_in[3];
  const float* Wk = (const float*)d_in[4];
  const float* bk = (const float*)d_in[5];
  const float* Wv = (const float*)d_in[6];
  const float* bv = (const float*)d_in[7];
  float* out = (float*)d_out;

  if (ws_size < 147259392u) return;  // uniform guard; ws layout below needs 147 MB

  char* ws = (char*)d_ws;
  bf16* Wt = (bf16*)(ws);               // 3*512*832*2   = 2,555,904
  bf16* xb = (bf16*)(ws + 2555904);     // 16384*832*2   = 27,262,976
  bf16* qk = (bf16*)(ws + 29818880);    // 2*16384*512*2 = 33,554,432 (Q then K)
  bf16* vt = (bf16*)(ws + 63373312);    // 8*512*2048*2  = 16,777,216 (V^T)
  bf16* S  = (bf16*)(ws + 80150528);    // 8*2048*2048*2 = 67,108,864

  prep_x<<<16384, 256, 0, stream>>>(patches, positions, xb);
  prep_w<<<dim3(16, 26, 3), dim3(32, 8), 0, stream>>>(Wq, Wk, Wv, Wt);
  gemm_qkv<<<1536, 256, 0, stream>>>(xb, Wt, bq, bk, bv, qk, vt);
  gemm_scores<<<2048, 256, 0, stream>>>(qk, S);
  softmax_rows<<<16384, 256, 0, stream>>>(S);
  gemm_pv<<<1024, 256, 0, stream>>>(S, vt, out);
}